// Round 8
// baseline (139.107 us; speedup 1.0000x reference)
//
#include <hip/hip_runtime.h>
#include <hip/hip_bf16.h>
#include <cstdint>

typedef __attribute__((ext_vector_type(4))) float f32x4;
typedef __attribute__((ext_vector_type(16))) float f32x16;
typedef __attribute__((ext_vector_type(8))) short s16x8;
typedef __attribute__((ext_vector_type(4))) unsigned short u16x4;
typedef __attribute__((ext_vector_type(4))) unsigned int u32x4;
typedef unsigned short u16;
typedef unsigned int u32;
typedef unsigned long long u64;

__device__ __forceinline__ float b2f(u16 u){ u32 v = ((u32)u)<<16; return __builtin_bit_cast(float, v); }
__device__ __forceinline__ u16 f2b(float f){
  __hip_bfloat16 h = __float2bfloat16(f);     // hw v_cvt path (RNE)
  return __builtin_bit_cast(u16, h);
}

__device__ __forceinline__ void gld16(const void* g, void* l){
  __builtin_amdgcn_global_load_lds((const __attribute__((address_space(1))) void*)g,
                                   (__attribute__((address_space(3))) void*)l, 16, 0, 0);
}

__device__ __forceinline__ f32x4 mfma16(s16x8 a, s16x8 b, f32x4 c){
  return __builtin_amdgcn_mfma_f32_16x16x32_bf16(a, b, c, 0, 0, 0);
}
__device__ __forceinline__ f32x16 mfma32(s16x8 a, s16x8 b, f32x16 c){
  return __builtin_amdgcn_mfma_f32_32x32x16_bf16(a, b, c, 0, 0, 0);
}

// workspace element offsets (u16 elements)
#define WS_XB   0u           // [4096][1024] bf16 x
#define WS_WQ   (4u<<20)
#define WS_WK   (5u<<20)
#define WS_WV   (6u<<20)
#define WS_WO   (7u<<20)
#define WS_Q    (8u<<20)     // (B,H,S,HD) bf16, RoPE'd, Q scaled by 0.125*log2(e)
#define WS_K    (12u<<20)    // (B,H,S,HD) bf16, RoPE'd
#define WS_VT   (16u<<20)    // [1024][4096] bf16  (V^T: rows h*64+hd, cols b*2048+s)
#define WS_AO   (20u<<20)    // (B,S,D) bf16 attention output

#define QSCALE 0.18033688f   // 0.125 * log2(e): QK^T result is in log2 domain

// ---------------- convert fp32 -> bf16 (x + 4 weights) ----------------
__global__ __launch_bounds__(256) void k_convert(const float* __restrict__ x,
    const float* __restrict__ wq, const float* __restrict__ wk,
    const float* __restrict__ wv, const float* __restrict__ wo,
    u16* __restrict__ ws){
  u32 idx = blockIdx.x*256u + threadIdx.x;   // f32x4 index; total 2M
  const float* src; u16* dst;
  if (idx < (1u<<20)) { src = x + (u64)idx*4u; dst = ws + WS_XB + (u64)idx*4u; }
  else {
    u32 widx = idx - (1u<<20);
    u32 wsel = widx >> 18;
    u32 off  = (widx & ((1u<<18)-1u)) * 4u;
    const float* sp = (wsel==0u)?wq:(wsel==1u)?wk:(wsel==2u)?wv:wo;
    src = sp + off; dst = ws + WS_WQ + (u64)wsel*(1u<<20) + off;
  }
  f32x4 v = *(const f32x4*)src;
  u16x4 o = { f2b(v[0]), f2b(v[1]), f2b(v[2]), f2b(v[3]) };
  *(u16x4*)dst = o;
}

// ---------------- GEMM: C[i][j] = sum_k A[i][k]*B[j][k] (both row-major, K=1024) -----
// BK=64, double-buffered: stage t+1 issued BEFORE compute of stage t, one barrier/step.
__global__ __launch_bounds__(256,2) void k_gemm(u16* __restrict__ ws, float* __restrict__ out,
    const float* __restrict__ fc, const float* __restrict__ fs, int pass){
  __shared__ char sm[65536];   // 2 stages x {A 16KB | B 16KB}; stage0 reused as C tile
  const u32 tid = threadIdx.x;
  const u32 w = tid>>6, l = tid&63u, g = l>>4, li = l&15u;
  const u32 wr = w>>1, wc = w&1u;
  u32 bx = blockIdx.x;

  const u16 *Ap, *Bp; u32 arow0, brow0; int mode;
  if (pass == 0) {
    u32 seg = bx >> 8, b2 = bx & 255u;
    if (seg < 2u) {
      Ap = ws + WS_XB; Bp = ws + (seg ? WS_WK : WS_WQ);
      arow0 = (b2 >> 3) * 128u; brow0 = (b2 & 7u) * 128u; mode = (int)seg;   // 0=Q 1=K
    } else {
      Ap = ws + WS_WV; Bp = ws + WS_XB;
      arow0 = (b2 >> 5) * 128u; brow0 = (b2 & 31u) * 128u; mode = 2;         // V^T
    }
  } else {
    Ap = ws + WS_AO; Bp = ws + WS_WO;
    arow0 = (bx >> 3) * 128u; brow0 = (bx & 7u) * 128u; mode = 3;            // O proj
  }

  f32x4 acc[4][4];
  #pragma unroll
  for (u32 m=0;m<4;++m)
    #pragma unroll
    for (u32 n=0;n<4;++n) acc[m][n] = 0.0f;

  auto STAGE_G = [&](u32 s, u32 t){
    const u32 k0 = t*64u;
    #pragma unroll
    for (u32 j = 0; j < 4u; ++j) {
      u32 p = w*4096u + j*1024u + l*16u;     // byte pos in 16KB tile
      u32 row = p >> 7, colb = p & 127u;
      u32 cS = colb ^ ((row & 7u) << 4);
      gld16(Ap + (u64)(arow0 + row)*1024u + k0 + (cS>>1), sm + s*32768u + w*4096u + j*1024u);
      gld16(Bp + (u64)(brow0 + row)*1024u + k0 + (cS>>1), sm + s*32768u + 16384u + w*4096u + j*1024u);
    }
  };

  STAGE_G(0u, 0u);
  __syncthreads();

  u32 cur = 0u;
  for (u32 t = 0; t < 16u; ++t) {
    if (t + 1u < 16u) STAGE_G(cur^1u, t+1u);   // issue-early prefetch
    const u32 cb = cur*32768u;
    s16x8 af[2][4], bf[2][4];
    #pragma unroll
    for (u32 kk=0;kk<2u;++kk){
      #pragma unroll
      for (u32 m=0;m<4;++m){
        u32 row = wr*64u + m*16u + li;
        af[kk][m] = *(const s16x8*)(sm + cb + row*128u + ((kk*64u + g*16u) ^ ((row&7u)<<4)));
      }
      #pragma unroll
      for (u32 n=0;n<4;++n){
        u32 row = wc*64u + n*16u + li;
        bf[kk][n] = *(const s16x8*)(sm + cb + 16384u + row*128u + ((kk*64u + g*16u) ^ ((row&7u)<<4)));
      }
    }
    #pragma unroll
    for (u32 kk=0;kk<2u;++kk)
      #pragma unroll
      for (u32 m=0;m<4;++m)
        #pragma unroll
        for (u32 n=0;n<4;++n)
          acc[m][n] = mfma16(af[kk][m], bf[kk][n], acc[m][n]);
    __syncthreads();   // drains prefetch (issued before compute) + protects reuse
    cur ^= 1u;
  }

  u16* qdst = ws + WS_Q; u16* kdst = ws + WS_K; u16* vtd = ws + WS_VT;
  if (mode <= 1) {
    #pragma unroll
    for (u32 m=0;m<4;++m)
      #pragma unroll
      for (u32 n=0;n<4;++n)
        #pragma unroll
        for (u32 q=0;q<4;++q){
          u32 row = wr*64u + m*16u + 4u*g + q;
          u32 colb = (wc*64u + n*16u + li)*2u;
          *(u16*)(sm + row*256u + (colb ^ ((row&7u)<<4))) = f2b(acc[m][n][q]);
        }
    __syncthreads();
    u32 row = tid >> 1, half = tid & 1u;
    u32 r = arow0 + row;
    u32 b = r >> 11, s = r & 2047u;
    u32 h = (brow0 >> 6) + half;
    float qs = (mode==0) ? QSCALE : 1.0f;
    u16* d = ((mode==0) ? qdst : kdst) + (u64)(((b<<4)+h)*2048u + s)*64u;
    #pragma unroll
    for (u32 u0=0; u0<8u; ++u0){
      s16x8 cv = *(const s16x8*)(sm + row*256u + ((half*128u + u0*16u) ^ ((row&7u)<<4)));
      f32x4 cvv = *(const f32x4*)(fc + s*32u + u0*4u);
      f32x4 svv = *(const f32x4*)(fs + s*32u + u0*4u);
      s16x8 o;
      #pragma unroll
      for (u32 i=0;i<4;++i){
        float t0 = b2f((u16)cv[2*i]), t1 = b2f((u16)cv[2*i+1]);
        o[2*i]   = (short)f2b((t0*cvv[i] - t1*svv[i])*qs);
        o[2*i+1] = (short)f2b((t0*svv[i] + t1*cvv[i])*qs);
      }
      *(s16x8*)(d + u0*8u) = o;
    }
  } else {
    #pragma unroll
    for (u32 m=0;m<4;++m){
      u32 r0 = arow0 + wr*64u + m*16u + 4u*g;
      #pragma unroll
      for (u32 n=0;n<4;++n){
        u32 c = brow0 + wc*64u + n*16u + li;
        #pragma unroll
        for (u32 q=0;q<4;++q){
          float v = acc[m][n][q];
          u32 r = r0 + q;
          if (mode == 2) vtd[(u64)r*4096u + c] = f2b(v);
          else           out[(u64)r*1024u + c] = v;
        }
      }
    }
  }
}

// ---------------- Flash attention (causal): 1 wave = 32 q-rows, barrier-free --------
// 32x32x16 MFMA, swapped QK (mfma(K,Q)) -> lane owns P-row of q=lane&31 across regs
// (kv = (r&3)+8*(r>>2)+4*(lane>>5), m74/m101 layout). K/V^T fragments read directly
// from global (L2-resident). No LDS, no barriers. Softmax: static-shift log2 domain,
// p=exp2(s); row sums via ones-MFMA (layout = o layout). P->PA via cvt_pk + shfl_xor(32).
__global__ __launch_bounds__(64) void k_attn(u16* __restrict__ ws){
  const u32 lane = threadIdx.x & 63u;
  const u32 q = lane & 31u, h = lane >> 5;
  const bool lo = lane < 32u;
  u32 u = blockIdx.x;
  u32 qs = 63u - (u >> 5);        // heavy strips first (LPT)
  u32 bh = u & 31u;
  u32 b = bh >> 4, head = bh & 15u;
  const u16* Q  = ws + WS_Q + (u64)bh*2048u*64u;
  const u16* Kp = ws + WS_K + (u64)bh*2048u*64u;
  const u16* Vt = ws + WS_VT + (u64)(head*64u)*4096u + b*2048u;
  u16* AO = ws + WS_AO;

  // Q fragments (B-operand): lane holds Q[qs*32+q][kk*16 + h*8 + j]
  s16x8 qf[4];
  #pragma unroll
  for (u32 kk=0;kk<4;++kk)
    qf[kk] = *(const s16x8*)(Q + (u64)(qs*32u + q)*64u + kk*16u + h*8u);

  s16x8 ones;
  #pragma unroll
  for (u32 i=0;i<8;++i) ones[i] = (short)0x3F80;   // bf16 1.0

  f32x16 o0, o1, lsum;
  #pragma unroll
  for (u32 r=0;r<16;++r){ o0[r]=0.0f; o1[r]=0.0f; lsum[r]=0.0f; }

  const u32 qg = qs*32u + q;
  const u32 nt = (qs >> 1) + 1u;
  for (u32 t = 0; t < nt; ++t) {
    const u32 kvb = t*64u;
    // V^T fragments (B-operand): lane holds V[kvb+ks*16+h*8+j][d*32+q]
    s16x8 vf[8];
    #pragma unroll
    for (u32 d=0; d<2u; ++d)
      #pragma unroll
      for (u32 ks=0; ks<4u; ++ks)
        vf[d*4u+ks] = *(const s16x8*)(Vt + (u64)(d*32u + q)*4096u + kvb + ks*16u + h*8u);
    // K fragments (A-operand): lane holds K[kvb+s*32+q][kk*16+h*8+j]
    s16x8 kf[8];
    #pragma unroll
    for (u32 s=0; s<2u; ++s)
      #pragma unroll
      for (u32 kk=0; kk<4u; ++kk)
        kf[s*4u+kk] = *(const s16x8*)(Kp + (u64)(kvb + s*32u + q)*64u + kk*16u + h*8u);

    // swapped QK^T: sv_s[r][lane] = P[kv=kvb+s*32+crow(r,h)][q]
    f32x16 sv0, sv1;
    #pragma unroll
    for (u32 r=0;r<16;++r){ sv0[r]=0.0f; sv1[r]=0.0f; }
    #pragma unroll
    for (u32 kk=0;kk<4u;++kk){
      sv0 = mfma32(kf[kk],     qf[kk], sv0);
      sv1 = mfma32(kf[4u+kk],  qf[kk], sv1);
    }
    if (t == nt - 1u) {   // only the last tile is causally partial
      #pragma unroll
      for (u32 r=0;r<16;++r){
        u32 kv0 = kvb + (r&3u) + 8u*(r>>2) + 4u*h;
        if (kv0       > qg) sv0[r] = -1e9f;
        if (kv0 + 32u > qg) sv1[r] = -1e9f;
      }
    }
    // p = exp2(s) in place
    #pragma unroll
    for (u32 r=0;r<16;++r){ sv0[r] = exp2f(sv0[r]); sv1[r] = exp2f(sv1[r]); }
    // pack to bf16 pairs: a[j] = cvt_pk(p[2j], p[2j+1])
    u32 a[16];
    #pragma unroll
    for (u32 j=0;j<8u;++j){
      asm("v_cvt_pk_bf16_f32 %0, %1, %2" : "=v"(a[j])    : "v"(sv0[2u*j]), "v"(sv0[2u*j+1u]));
      asm("v_cvt_pk_bf16_f32 %0, %1, %2" : "=v"(a[8u+j]) : "v"(sv1[2u*j]), "v"(sv1[2u*j+1u]));
    }
    // build PA fragments: pa[ks] word u: kv = kvb+ks*16+h*8+2u..+1
    //   u0 = {x.lo, y.lo}, u1 likewise; u2 = {x.hi, y.hi}  for pairs x=a[b0+i], y=a[b0+i+2]
    #pragma unroll
    for (u32 ks=0; ks<4u; ++ks){
      u32 b0 = ks*4u;
      u32 x0 = a[b0], x1 = a[b0+1u], y0 = a[b0+2u], y1 = a[b0+3u];
      u32 y0s = __shfl_xor(y0, 32), y1s = __shfl_xor(y1, 32);
      u32 x0s = __shfl_xor(x0, 32), x1s = __shfl_xor(x1, 32);
      u32x4 paw = { lo ? x0 : y0s,  lo ? x1 : y1s,
                    lo ? x0s : y0,  lo ? x1s : y1 };
      s16x8 pa = __builtin_bit_cast(s16x8, paw);
      lsum = mfma32(pa, ones, lsum);
      o0 = mfma32(pa, vf[ks],     o0);
      o1 = mfma32(pa, vf[4u+ks],  o1);
    }
  }

  // epilogue: normalize, write (B,S,D) bf16. o row = crow(r,h), col = lane&31 (+32d)
  #pragma unroll
  for (u32 r=0;r<16;++r){
    float inv = 1.0f / lsum[r];
    u32 row = b*2048u + qs*32u + (r&3u) + 8u*(r>>2) + 4u*h;
    u64 base = (u64)row*1024u + head*64u + q;
    AO[base]       = f2b(o0[r] * inv);
    AO[base + 32u] = f2b(o1[r] * inv);
  }
}

extern "C" void kernel_launch(void* const* d_in, const int* in_sizes, int n_in,
                              void* d_out, int out_size, void* d_ws, size_t ws_size,
                              hipStream_t stream) {
  const float* x  = (const float*)d_in[0];
  const float* fc = (const float*)d_in[1];
  const float* fs = (const float*)d_in[2];
  // d_in[3] = mask (unused; causal mask applied analytically)
  const float* wq = (const float*)d_in[4];
  const float* wk = (const float*)d_in[5];
  const float* wv = (const float*)d_in[6];
  const float* wo = (const float*)d_in[7];
  u16* ws = (u16*)d_ws;
  float* out = (float*)d_out;

  k_convert<<<8192, 256, 0, stream>>>(x, wq, wk, wv, wo, ws);
  k_gemm  <<<768,  256, 0, stream>>>(ws, out, fc, fs, 0);   // Q,K (RoPE fused), V^T
  k_attn  <<<2048, 64,  0, stream>>>(ws);                   // causal flash attention
  k_gemm  <<<256,  256, 0, stream>>>(ws, out, fc, fs, 1);   // output projection -> fp32
}

// Round 9
// 109.468 us; speedup vs baseline: 1.2708x; 1.2708x over previous
//
#include <hip/hip_runtime.h>
#include <hip/hip_bf16.h>
#include <cstdint>

typedef __attribute__((ext_vector_type(4))) float f32x4;
typedef __attribute__((ext_vector_type(8))) short s16x8;
typedef __attribute__((ext_vector_type(4))) unsigned short u16x4;
typedef unsigned short u16;
typedef unsigned int u32;
typedef unsigned long long u64;

__device__ __forceinline__ float b2f(u16 u){ u32 v = ((u32)u)<<16; return __builtin_bit_cast(float, v); }
__device__ __forceinline__ u16 f2b(float f){
  __hip_bfloat16 h = __float2bfloat16(f);     // hw v_cvt path (RNE)
  return __builtin_bit_cast(u16, h);
}

__device__ __forceinline__ void gld16(const void* g, void* l){
  __builtin_amdgcn_global_load_lds((const __attribute__((address_space(1))) void*)g,
                                   (__attribute__((address_space(3))) void*)l, 16, 0, 0);
}

__device__ __forceinline__ f32x4 mfma16(s16x8 a, s16x8 b, f32x4 c){
  return __builtin_amdgcn_mfma_f32_16x16x32_bf16(a, b, c, 0, 0, 0);
}

// workspace element offsets (u16 elements)
#define WS_XB   0u           // [4096][1024] bf16 x
#define WS_WQ   (4u<<20)
#define WS_WK   (5u<<20)
#define WS_WV   (6u<<20)
#define WS_WO   (7u<<20)
#define WS_Q    (8u<<20)     // (B,H,S,HD) bf16, RoPE'd, Q scaled by 0.125*log2(e)
#define WS_K    (12u<<20)    // (B,H,S,HD) bf16, RoPE'd
#define WS_VT   (16u<<20)    // [1024][4096] bf16  (V^T: rows h*64+hd, cols b*2048+s)
#define WS_AO   (20u<<20)    // (B,S,D) bf16 attention output

#define QSCALE 0.18033688f   // 0.125 * log2(e): QK^T result is in log2 domain

// ---------------- convert fp32 -> bf16 (x + 4 weights) ----------------
__global__ __launch_bounds__(256) void k_convert(const float* __restrict__ x,
    const float* __restrict__ wq, const float* __restrict__ wk,
    const float* __restrict__ wv, const float* __restrict__ wo,
    u16* __restrict__ ws){
  u32 idx = blockIdx.x*256u + threadIdx.x;   // f32x4 index; total 2M
  const float* src; u16* dst;
  if (idx < (1u<<20)) { src = x + (u64)idx*4u; dst = ws + WS_XB + (u64)idx*4u; }
  else {
    u32 widx = idx - (1u<<20);
    u32 wsel = widx >> 18;
    u32 off  = (widx & ((1u<<18)-1u)) * 4u;
    const float* sp = (wsel==0u)?wq:(wsel==1u)?wk:(wsel==2u)?wv:wo;
    src = sp + off; dst = ws + WS_WQ + (u64)wsel*(1u<<20) + off;
  }
  f32x4 v = *(const f32x4*)src;
  u16x4 o = { f2b(v[0]), f2b(v[1]), f2b(v[2]), f2b(v[3]) };
  *(u16x4*)dst = o;
}

// ---------------- GEMM: C[i][j] = sum_k A[i][k]*B[j][k] (both row-major, K=1024) -----
// BK=64, double-buffered: stage t+1 issued BEFORE compute of stage t, one barrier/step.
__global__ __launch_bounds__(256,2) void k_gemm(u16* __restrict__ ws, float* __restrict__ out,
    const float* __restrict__ fc, const float* __restrict__ fs, int pass){
  __shared__ char sm[65536];   // 2 stages x {A 16KB | B 16KB}; stage0 reused as C tile
  const u32 tid = threadIdx.x;
  const u32 w = tid>>6, l = tid&63u, g = l>>4, li = l&15u;
  const u32 wr = w>>1, wc = w&1u;
  u32 bx = blockIdx.x;

  const u16 *Ap, *Bp; u32 arow0, brow0; int mode;
  if (pass == 0) {
    u32 seg = bx >> 8, b2 = bx & 255u;
    if (seg < 2u) {
      Ap = ws + WS_XB; Bp = ws + (seg ? WS_WK : WS_WQ);
      arow0 = (b2 >> 3) * 128u; brow0 = (b2 & 7u) * 128u; mode = (int)seg;   // 0=Q 1=K
    } else {
      Ap = ws + WS_WV; Bp = ws + WS_XB;
      arow0 = (b2 >> 5) * 128u; brow0 = (b2 & 31u) * 128u; mode = 2;         // V^T
    }
  } else {
    Ap = ws + WS_AO; Bp = ws + WS_WO;
    arow0 = (bx >> 3) * 128u; brow0 = (bx & 7u) * 128u; mode = 3;            // O proj
  }

  f32x4 acc[4][4];
  #pragma unroll
  for (u32 m=0;m<4;++m)
    #pragma unroll
    for (u32 n=0;n<4;++n) acc[m][n] = 0.0f;

  auto STAGE_G = [&](u32 s, u32 t){
    const u32 k0 = t*64u;
    #pragma unroll
    for (u32 j = 0; j < 4u; ++j) {
      u32 p = w*4096u + j*1024u + l*16u;     // byte pos in 16KB tile
      u32 row = p >> 7, colb = p & 127u;
      u32 cS = colb ^ ((row & 7u) << 4);
      gld16(Ap + (u64)(arow0 + row)*1024u + k0 + (cS>>1), sm + s*32768u + w*4096u + j*1024u);
      gld16(Bp + (u64)(brow0 + row)*1024u + k0 + (cS>>1), sm + s*32768u + 16384u + w*4096u + j*1024u);
    }
  };

  STAGE_G(0u, 0u);
  __syncthreads();

  u32 cur = 0u;
  for (u32 t = 0; t < 16u; ++t) {
    if (t + 1u < 16u) STAGE_G(cur^1u, t+1u);   // issue-early prefetch
    const u32 cb = cur*32768u;
    s16x8 af[2][4], bf[2][4];
    #pragma unroll
    for (u32 kk=0;kk<2u;++kk){
      #pragma unroll
      for (u32 m=0;m<4;++m){
        u32 row = wr*64u + m*16u + li;
        af[kk][m] = *(const s16x8*)(sm + cb + row*128u + ((kk*64u + g*16u) ^ ((row&7u)<<4)));
      }
      #pragma unroll
      for (u32 n=0;n<4;++n){
        u32 row = wc*64u + n*16u + li;
        bf[kk][n] = *(const s16x8*)(sm + cb + 16384u + row*128u + ((kk*64u + g*16u) ^ ((row&7u)<<4)));
      }
    }
    #pragma unroll
    for (u32 kk=0;kk<2u;++kk)
      #pragma unroll
      for (u32 m=0;m<4;++m)
        #pragma unroll
        for (u32 n=0;n<4;++n)
          acc[m][n] = mfma16(af[kk][m], bf[kk][n], acc[m][n]);
    __syncthreads();   // drains prefetch (issued before compute) + protects reuse
    cur ^= 1u;
  }

  u16* qdst = ws + WS_Q; u16* kdst = ws + WS_K; u16* vtd = ws + WS_VT;
  if (mode <= 1) {
    #pragma unroll
    for (u32 m=0;m<4;++m)
      #pragma unroll
      for (u32 n=0;n<4;++n)
        #pragma unroll
        for (u32 q=0;q<4;++q){
          u32 row = wr*64u + m*16u + 4u*g + q;
          u32 colb = (wc*64u + n*16u + li)*2u;
          *(u16*)(sm + row*256u + (colb ^ ((row&7u)<<4))) = f2b(acc[m][n][q]);
        }
    __syncthreads();
    u32 row = tid >> 1, half = tid & 1u;
    u32 r = arow0 + row;
    u32 b = r >> 11, s = r & 2047u;
    u32 h = (brow0 >> 6) + half;
    float qs = (mode==0) ? QSCALE : 1.0f;
    u16* d = ((mode==0) ? qdst : kdst) + (u64)(((b<<4)+h)*2048u + s)*64u;
    #pragma unroll
    for (u32 u0=0; u0<8u; ++u0){
      s16x8 cv = *(const s16x8*)(sm + row*256u + ((half*128u + u0*16u) ^ ((row&7u)<<4)));
      f32x4 cvv = *(const f32x4*)(fc + s*32u + u0*4u);
      f32x4 svv = *(const f32x4*)(fs + s*32u + u0*4u);
      s16x8 o;
      #pragma unroll
      for (u32 i=0;i<4;++i){
        float t0 = b2f((u16)cv[2*i]), t1 = b2f((u16)cv[2*i+1]);
        o[2*i]   = (short)f2b((t0*cvv[i] - t1*svv[i])*qs);
        o[2*i+1] = (short)f2b((t0*svv[i] + t1*cvv[i])*qs);
      }
      *(s16x8*)(d + u0*8u) = o;
    }
  } else {
    #pragma unroll
    for (u32 m=0;m<4;++m){
      u32 r0 = arow0 + wr*64u + m*16u + 4u*g;
      #pragma unroll
      for (u32 n=0;n<4;++n){
        u32 c = brow0 + wc*64u + n*16u + li;
        #pragma unroll
        for (u32 q=0;q<4;++q){
          float v = acc[m][n][q];
          u32 r = r0 + q;
          if (mode == 2) vtd[(u64)r*4096u + c] = f2b(v);
          else           out[(u64)r*1024u + c] = v;
        }
      }
    }
  }
}

// ---------------- Flash attention (causal), 4 waves x 16 q-rows, KVBLK=64 ----------------
// R7 structure (grid 1024, LPT heavy-first, dbuf issue-early) with P-LDS swizzled
// instead of padded: LDS 40960B -> 4 blocks/CU (16 waves/CU), +33% TLP vs R7.
__global__ __launch_bounds__(256) void k_attn(u16* __restrict__ ws){
  __shared__ char sm[40960];  // 2 stages x {K 8KB | V 8KB} | P 4 x 2048B (swizzled)
  const u32 tid = threadIdx.x;
  const u32 w = tid>>6, l = tid&63u, g = l>>4, li = l&15u;
  u32 bx = blockIdx.x;
  u32 qt = 31u - (bx >> 5);     // heavy q-tiles dispatched first (LPT)
  u32 bh = bx & 31u;
  u32 b = bh >> 4, h = bh & 15u;
  const u16* Q  = ws + WS_Q + (u64)bh*2048u*64u;
  const u16* Kp = ws + WS_K + (u64)bh*2048u*64u;
  const u16* Vt = ws + WS_VT + (u64)(h*64u)*4096u + b*2048u;
  u16* AO = ws + WS_AO;
  const u32 qw = qt*64u + w*16u;

  s16x8 qa[2];
  #pragma unroll
  for (u32 kk=0;kk<2;++kk)
    qa[kk] = *(const s16x8*)(Q + (u64)(qw + li)*64u + kk*32u + g*8u);

  s16x8 ones;
  #pragma unroll
  for (u32 i=0;i<8;++i) ones[i] = (short)0x3F80;   // bf16 1.0

  f32x4 o[4]; f32x4 lsum;
  #pragma unroll
  for (u32 n=0;n<4;++n) o[n] = 0.0f;
  lsum = 0.0f;

  char* pl = sm + 32768 + w*2048u;   // 16 rows x 128B, XOR-swizzled
  const u32 nt = qt + 1u;

  // stage K/V tile (64 rows) into stage s from kv base row kvb
  auto STAGE = [&](u32 s, u32 kvb){
    #pragma unroll
    for (u32 j=0;j<2u;++j){
      u32 p = (w*2u+j)*1024u + l*16u;
      u32 row = p >> 7, colb = p & 127u;
      u32 cS = colb ^ ((row & 7u) << 4);
      gld16(Kp + (u64)(kvb + row)*64u + (cS>>1), sm + s*16384u + (w*2u+j)*1024u);
      gld16(Vt + (u64)row*4096u + kvb + (cS>>1), sm + s*16384u + 8192u + (w*2u+j)*1024u);
    }
  };

  STAGE(0u, 0u);
  __syncthreads();

  u32 cur = 0u;
  for (u32 t = 0; t < nt; ++t) {
    const u32 kvb = t*64u;
    if (t + 1u < nt) STAGE(cur^1u, kvb + 64u);   // issue-early prefetch
    const u32 cb = cur*16384u;

    f32x4 sv[4];
    #pragma unroll
    for (u32 n=0;n<4;++n) sv[n] = 0.0f;
    #pragma unroll
    for (u32 n=0;n<4;++n){
      u32 kvr = n*16u + li;
      #pragma unroll
      for (u32 kk=0;kk<2u;++kk){
        s16x8 kf = *(const s16x8*)(sm + cb + kvr*128u + ((kk*64u + g*16u) ^ ((kvr&7u)<<4)));
        sv[n] = mfma16(qa[kk], kf, sv[n]);
      }
    }
    if (t == nt - 1u) {   // only the last tile is causally partial
      #pragma unroll
      for (u32 n=0;n<4;++n)
        #pragma unroll
        for (u32 q=0;q<4;++q){
          u32 qr = qw + 4u*g + q;
          u32 kc = kvb + n*16u + li;
          if (kc > qr) sv[n][q] = -1e9f;
        }
    }
    // p = exp2(s2) -> bf16 P in LDS (swizzled rows: col*2 ^ ((row&7)<<4))
    #pragma unroll
    for (u32 n=0;n<4;++n)
      #pragma unroll
      for (u32 q=0;q<4;++q){
        u32 row = 4u*g + q;
        *(u16*)(pl + row*128u + (((n*16u + li)*2u) ^ ((row&7u)<<4))) = f2b(exp2f(sv[n][q]));
      }
    // PV + row-sum (ones-column MFMA)
    #pragma unroll
    for (u32 kk=0;kk<2u;++kk){
      s16x8 pa = *(const s16x8*)(pl + li*128u + ((kk*64u + g*16u) ^ ((li&7u)<<4)));
      lsum = mfma16(pa, ones, lsum);
      #pragma unroll
      for (u32 n=0;n<4;++n){
        u32 hr = n*16u + li;
        s16x8 vf = *(const s16x8*)(sm + cb + 8192u + hr*128u + ((kk*64u + g*16u) ^ ((hr&7u)<<4)));
        o[n] = mfma16(pa, vf, o[n]);
      }
    }
    __syncthreads();   // drains prefetch (issued before compute) + protects buffer reuse
    cur ^= 1u;
  }

  // epilogue: normalize by MFMA row sums, write (B,S,D) bf16
  #pragma unroll
  for (u32 q=0;q<4;++q){
    float inv = 1.0f / lsum[q];
    u32 qr = qw + 4u*g + q;
    #pragma unroll
    for (u32 n=0;n<4;++n){
      u32 hd = n*16u + li;
      AO[((u64)(b*2048u + qr))*1024u + h*64u + hd] = f2b(o[n][q] * inv);
    }
  }
}

extern "C" void kernel_launch(void* const* d_in, const int* in_sizes, int n_in,
                              void* d_out, int out_size, void* d_ws, size_t ws_size,
                              hipStream_t stream) {
  const float* x  = (const float*)d_in[0];
  const float* fc = (const float*)d_in[1];
  const float* fs = (const float*)d_in[2];
  // d_in[3] = mask (unused; causal mask applied analytically)
  const float* wq = (const float*)d_in[4];
  const float* wk = (const float*)d_in[5];
  const float* wv = (const float*)d_in[6];
  const float* wo = (const float*)d_in[7];
  u16* ws = (u16*)d_ws;
  float* out = (float*)d_out;

  k_convert<<<8192, 256, 0, stream>>>(x, wq, wk, wv, wo, ws);
  k_gemm  <<<768,  256, 0, stream>>>(ws, out, fc, fs, 0);   // Q,K (RoPE fused), V^T
  k_attn  <<<1024, 256, 0, stream>>>(ws);                   // causal flash attention
  k_gemm  <<<256,  256, 0, stream>>>(ws, out, fc, fs, 1);   // output projection -> fp32
}